// Round 22
// baseline (310.894 us; speedup 1.0000x reference)
//
#include <hip/hip_runtime.h>
#include <math.h>

typedef _Float16 f16;
typedef _Float16 f16x2 __attribute__((ext_vector_type(2)));
typedef _Float16 f16x8 __attribute__((ext_vector_type(8)));
typedef __fp16 fp16x2 __attribute__((ext_vector_type(2)));
typedef float f32x4 __attribute__((ext_vector_type(4)));

union F2U { f16x2 h; fp16x2 p; unsigned u; };
union U2H { uint2 q; f16x2 h[2]; f16 f[4]; };
union U4H { uint4 q; f16x2 h[4]; f16 f[8]; };
union V8H { f16x8 v; f16x2 h[4]; f16 f[8]; uint4 q; };

__device__ __forceinline__ f16x2 uAsH(unsigned u) { F2U c; c.u = u; return c.h; }
__device__ __forceinline__ unsigned hAsU(f16x2 h) { F2U c; c.h = h; return c.u; }
__device__ __forceinline__ unsigned pAsU(fp16x2 p) { F2U c; c.p = p; return c.u; }

__device__ __forceinline__ f16x8 ld8cvt(const float* p) {
    float4 a = *(const float4*)p;
    float4 b = *(const float4*)(p + 4);
    V8H r;
    r.f[0] = (f16)a.x; r.f[1] = (f16)a.y; r.f[2] = (f16)a.z; r.f[3] = (f16)a.w;
    r.f[4] = (f16)b.x; r.f[5] = (f16)b.y; r.f[6] = (f16)b.z; r.f[7] = (f16)b.w;
    return r.v;
}

constexpr size_t PL = (size_t)512 * 512 * 96;

// ---------------------------------------------------------------------------
// K0: x f32 -> f16 (one pass; xh is L3-resident for k12's 6x re-reads).
// ---------------------------------------------------------------------------
__global__ __launch_bounds__(256) void kcvt(const float* __restrict__ x,
                                            f16* __restrict__ xh)
{
    const int id = blockIdx.x * 256 + threadIdx.x;   // 786432 threads
    #pragma unroll
    for (int it = 0; it < 4; ++it) {
        size_t i = ((size_t)id + (size_t)it * 786432) * 8;
        V8H r; r.v = ld8cvt(x + i);
        *(uint4*)(xh + i) = r.q;
    }
}

// ---------------------------------------------------------------------------
// K12 v11 (round-21 verbatim, 116 us): channel-split fused pointwise+
// depthwise reading pre-converted f16 xh. 1-D grid 3072, batch-major decode.
// block 512. Outputs: q,k [b][n][c]; v [b][c][n].
// ---------------------------------------------------------------------------
__global__ __launch_bounds__(512) void k12_fused(
    const f16* __restrict__ xh,
    const float* __restrict__ wq1, const float* __restrict__ bq1,
    const float* __restrict__ wk1, const float* __restrict__ bk1,
    const float* __restrict__ wv1, const float* __restrict__ bv1,
    const float* __restrict__ wqd, const float* __restrict__ bqd,
    const float* __restrict__ wkd, const float* __restrict__ bkd,
    const float* __restrict__ wvd, const float* __restrict__ bvd,
    f16* __restrict__ qo, f16* __restrict__ ko, f16* __restrict__ vo)
{
    __shared__ __align__(16) char sm[74400];

    const int tid = threadIdx.x;
    const int id = blockIdx.x;
    const int b = id / 6;
    const int r6 = id - b * 6;
    const int which = r6 >> 1;
    const int chalf = r6 & 1;
    const int ch0 = chalf * 48;
    const int wv_ = tid >> 6, lane = tid & 63, lr = lane & 15, lk = lane >> 4;

    const float* w1 = (which == 0) ? wq1 : ((which == 1) ? wk1 : wv1);
    const float* b1 = (which == 0) ? bq1 : ((which == 1) ? bk1 : bv1);
    const float* wd = (which == 0) ? wqd : ((which == 1) ? wkd : wvd);
    const float* bd = (which == 0) ? bqd : ((which == 1) ? bkd : bvd);
    const f16* xb = xh + (size_t)b * 512 * 96;

    if (which < 2) {
        f16*      slab = (f16*)sm;                 // [512][60] GEMM out
        f16*      Wsh  = (f16*)(sm + 61440);       // [48][104] pointwise w
        unsigned* wdh  = (unsigned*)(sm + 71424);  // [27][24] u32
        float*    bl1  = (float*)(sm + 74016);
        float*    bld  = (float*)(sm + 74208);

        #pragma unroll
        for (int it = 0; it < 3; ++it) {
            int g = tid + it * 512;
            if (g < 1152) {
                int i = g * 4;
                int co = i / 96, ci = i % 96;
                float4 v4 = *(const float4*)(w1 + (size_t)(ch0 + co) * 96 + ci);
                f16x2 h01 = { (f16)v4.x, (f16)v4.y };
                f16x2 h23 = { (f16)v4.z, (f16)v4.w };
                uint2 st; st.x = hAsU(h01); st.y = hAsU(h23);
                *(uint2*)(Wsh + co * 104 + ci) = st;
            }
        }
        for (int ii = tid; ii < 1296; ii += 512) {
            int lc = ii / 27, t2 = ii % 27;
            ((f16*)wdh)[t2 * 48 + lc] = (f16)wd[(ch0 + lc) * 27 + t2];
        }
        if (tid < 48) { bl1[tid] = b1[ch0 + tid]; bld[tid] = bd[ch0 + tid]; }
        __syncthreads();

        f32x4 acc[4][3];
        #pragma unroll
        for (int pg = 0; pg < 4; ++pg)
            #pragma unroll
            for (int cg = 0; cg < 3; ++cg) acc[pg][cg] = f32x4{0.f, 0.f, 0.f, 0.f};
        #pragma unroll
        for (int ks = 0; ks < 3; ++ks) {
            f16x8 bfr[3];
            #pragma unroll
            for (int cg = 0; cg < 3; ++cg)
                bfr[cg] = *(const f16x8*)(Wsh + (cg * 16 + lr) * 104 + ks * 32 + lk * 8);
            #pragma unroll
            for (int pg = 0; pg < 4; ++pg) {
                f16x8 a = *(const f16x8*)(xb + (size_t)(wv_ * 64 + pg * 16 + lr) * 96 + ks * 32 + lk * 8);
                #pragma unroll
                for (int cg = 0; cg < 3; ++cg)
                    acc[pg][cg] = __builtin_amdgcn_mfma_f32_16x16x32_f16(bfr[cg], a, acc[pg][cg], 0, 0, 0);
            }
        }
        __syncthreads();

        #pragma unroll
        for (int pg = 0; pg < 4; ++pg) {
            int pos = wv_ * 64 + pg * 16 + lr;
            #pragma unroll
            for (int cg = 0; cg < 3; ++cg) {
                float4 bv4 = *(const float4*)&bl1[cg * 16 + lk * 4];
                f16x2 h01 = { (f16)(acc[pg][cg][0] + bv4.x), (f16)(acc[pg][cg][1] + bv4.y) };
                f16x2 h23 = { (f16)(acc[pg][cg][2] + bv4.z), (f16)(acc[pg][cg][3] + bv4.w) };
                uint2 st; st.x = hAsU(h01); st.y = hAsU(h23);
                *(uint2*)(slab + pos * 60 + cg * 16 + lk * 4) = st;
            }
        }
        __syncthreads();

        f16* outb = ((which == 0) ? qo : ko) + (size_t)b * 512 * 96;
        #pragma unroll
        for (int half = 0; half < 2; ++half) {
            if (half == 1 && tid >= 256) break;
            const int u = half * 512 + tid;
            const int r = u / 12;
            const int g4 = u - r * 12;
            const int dd = r >> 3, hh = r & 7;
            const int col = g4 * 4;
            float mo[8][4];
            {
                float4 b0 = *(const float4*)&bld[col];
                #pragma unroll
                for (int w = 0; w < 8; ++w) {
                    mo[w][0] = b0.x; mo[w][1] = b0.y; mo[w][2] = b0.z; mo[w][3] = b0.w;
                }
            }
            #pragma unroll
            for (int kd = 0; kd < 3; ++kd) {
                const int d2 = dd + kd - 1;
                const bool vd = (unsigned)d2 < 8u;
                f16x2 pa[8][2];
                #pragma unroll
                for (int w = 0; w < 8; ++w) {
                    pa[w][0] = f16x2{0, 0}; pa[w][1] = f16x2{0, 0};
                }
                #pragma unroll
                for (int kh = 0; kh < 3; ++kh) {
                    const int h2 = hh + kh - 1;
                    const unsigned vm = (vd && ((unsigned)h2 < 8u)) ? 0xFFFFFFFFu : 0u;
                    const int base = (vm ? (d2 * 64 + h2 * 8) : 0) * 60 + col;
                    U2H in[8];
                    #pragma unroll
                    for (int w2 = 0; w2 < 8; ++w2)
                        in[w2].q = *(const uint2*)(slab + base + w2 * 60);
                    const int t0 = (kd * 3 + kh) * 3;
                    f16x2 wt0[2], wt1[2], wt2[2];
                    #pragma unroll
                    for (int p = 0; p < 2; ++p) {
                        wt0[p] = uAsH(wdh[(t0 + 0) * 24 + g4 * 2 + p] & vm);
                        wt1[p] = uAsH(wdh[(t0 + 1) * 24 + g4 * 2 + p] & vm);
                        wt2[p] = uAsH(wdh[(t0 + 2) * 24 + g4 * 2 + p] & vm);
                    }
                    #pragma unroll
                    for (int w = 0; w < 8; ++w) {
                        #pragma unroll
                        for (int p = 0; p < 2; ++p) {
                            f16x2 s = pa[w][p];
                            s = in[w].h[p] * wt1[p] + s;
                            if (w > 0) s = in[w - 1].h[p] * wt0[p] + s;
                            if (w < 7) s = in[w + 1].h[p] * wt2[p] + s;
                            pa[w][p] = s;
                        }
                    }
                }
                #pragma unroll
                for (int w = 0; w < 8; ++w)
                    #pragma unroll
                    for (int p = 0; p < 2; ++p) {
                        mo[w][2 * p]     += (float)pa[w][p].x;
                        mo[w][2 * p + 1] += (float)pa[w][p].y;
                    }
            }
            #pragma unroll
            for (int w = 0; w < 8; ++w) {
                f16x2 h0 = { (f16)mo[w][0], (f16)mo[w][1] };
                f16x2 h1 = { (f16)mo[w][2], (f16)mo[w][3] };
                uint2 st; st.x = hAsU(h0); st.y = hAsU(h1);
                *(uint2*)(outb + (size_t)(r * 8 + w) * 96 + ch0 + col) = st;
            }
        }
    } else {
        f16*      Vsh = (f16*)sm;                  // [48][520] GEMM out
        f16*      Wsh = (f16*)(sm + 49920);        // [48][104]
        unsigned* wdp = (unsigned*)(sm + 59904);   // [48][27]
        float*    bl1 = (float*)(sm + 65088);
        float*    bld = (float*)(sm + 65280);

        #pragma unroll
        for (int it = 0; it < 3; ++it) {
            int g = tid + it * 512;
            if (g < 1152) {
                int i = g * 4;
                int co = i / 96, ci = i % 96;
                float4 v4 = *(const float4*)(w1 + (size_t)(ch0 + co) * 96 + ci);
                f16x2 h01 = { (f16)v4.x, (f16)v4.y };
                f16x2 h23 = { (f16)v4.z, (f16)v4.w };
                uint2 st; st.x = hAsU(h01); st.y = hAsU(h23);
                *(uint2*)(Wsh + co * 104 + ci) = st;
            }
        }
        for (int ii = tid; ii < 1296; ii += 512) {
            int lc = ii / 27, t2 = ii % 27;
            f16 hh = (f16)wd[(ch0 + lc) * 27 + t2];
            f16x2 hp = { hh, hh };
            wdp[lc * 27 + t2] = hAsU(hp);
        }
        if (tid < 48) { bl1[tid] = b1[ch0 + tid]; bld[tid] = bd[ch0 + tid]; }
        __syncthreads();

        f32x4 acc[4][3];
        #pragma unroll
        for (int pg = 0; pg < 4; ++pg)
            #pragma unroll
            for (int cg = 0; cg < 3; ++cg) acc[pg][cg] = f32x4{0.f, 0.f, 0.f, 0.f};
        #pragma unroll
        for (int ks = 0; ks < 3; ++ks) {
            f16x8 bfr[3];
            #pragma unroll
            for (int cg = 0; cg < 3; ++cg)
                bfr[cg] = *(const f16x8*)(Wsh + (cg * 16 + lr) * 104 + ks * 32 + lk * 8);
            #pragma unroll
            for (int pg = 0; pg < 4; ++pg) {
                f16x8 a = *(const f16x8*)(xb + (size_t)(wv_ * 64 + pg * 16 + lr) * 96 + ks * 32 + lk * 8);
                #pragma unroll
                for (int cg = 0; cg < 3; ++cg)
                    acc[pg][cg] = __builtin_amdgcn_mfma_f32_16x16x32_f16(a, bfr[cg], acc[pg][cg], 0, 0, 0);
            }
        }
        __syncthreads();

        #pragma unroll
        for (int pg = 0; pg < 4; ++pg) {
            int pos = wv_ * 64 + pg * 16 + lk * 4;
            #pragma unroll
            for (int cg = 0; cg < 3; ++cg) {
                float bv = bl1[cg * 16 + lr];
                int lc = cg * 16 + lr;
                f16x2 h01 = { (f16)(acc[pg][cg][0] + bv), (f16)(acc[pg][cg][1] + bv) };
                f16x2 h23 = { (f16)(acc[pg][cg][2] + bv), (f16)(acc[pg][cg][3] + bv) };
                uint2 st; st.x = hAsU(h01); st.y = hAsU(h23);
                *(uint2*)(Vsh + lc * 520 + pos) = st;
            }
        }
        __syncthreads();

        f16* outb = vo + (size_t)b * 96 * 512;
        #pragma unroll
        for (int j = 0; j < 6; ++j) {
            int u = tid + j * 512;
            int c = u >> 6, dh = u & 63;
            int dd = dh >> 3, hh2 = dh & 7;
            f16x2 A0[4], A1[4], A2[4];
            #pragma unroll
            for (int p = 0; p < 4; ++p) {
                A0[p] = f16x2{0, 0}; A1[p] = f16x2{0, 0}; A2[p] = f16x2{0, 0};
            }
            #pragma unroll
            for (int kd = 0; kd < 3; ++kd) {
                int d2 = dd + kd - 1;
                unsigned vd_ = ((unsigned)d2 < 8u) ? 0xFFFFFFFFu : 0u;
                #pragma unroll
                for (int kh = 0; kh < 3; ++kh) {
                    int h2 = hh2 + kh - 1;
                    unsigned vm = ((((unsigned)h2 < 8u) ? 0xFFFFFFFFu : 0u) & vd_);
                    int rowoff = vm ? ((d2 * 8 + h2) * 8) : 0;
                    uint4 rw = *(const uint4*)(Vsh + c * 520 + rowoff);
                    unsigned r0 = rw.x, r1 = rw.y, r2 = rw.z, r3 = rw.w;
                    unsigned ms0 = r0 << 16;
                    unsigned ms1 = (r1 << 16) | (r0 >> 16);
                    unsigned ms2 = (r2 << 16) | (r1 >> 16);
                    unsigned ms3 = (r3 << 16) | (r2 >> 16);
                    unsigned ms4 = r3 >> 16;
                    int t0 = kd * 9 + kh * 3;
                    f16x2 w0 = uAsH(wdp[c * 27 + t0]     & vm);
                    f16x2 w1 = uAsH(wdp[c * 27 + t0 + 1] & vm);
                    f16x2 w2 = uAsH(wdp[c * 27 + t0 + 2] & vm);
                    f16x2* acc2 = (kd == 0) ? A0 : ((kd == 1) ? A1 : A2);
                    acc2[0] = uAsH(ms0) * w0 + acc2[0];
                    acc2[1] = uAsH(ms1) * w0 + acc2[1];
                    acc2[2] = uAsH(ms2) * w0 + acc2[2];
                    acc2[3] = uAsH(ms3) * w0 + acc2[3];
                    acc2[0] = uAsH(r0) * w1 + acc2[0];
                    acc2[1] = uAsH(r1) * w1 + acc2[1];
                    acc2[2] = uAsH(r2) * w1 + acc2[2];
                    acc2[3] = uAsH(r3) * w1 + acc2[3];
                    acc2[0] = uAsH(ms1) * w2 + acc2[0];
                    acc2[1] = uAsH(ms2) * w2 + acc2[1];
                    acc2[2] = uAsH(ms3) * w2 + acc2[2];
                    acc2[3] = uAsH(ms4) * w2 + acc2[3];
                }
            }
            float bv = bld[c];
            unsigned ow[4];
            #pragma unroll
            for (int p = 0; p < 4; ++p) {
                float lo = (float)A0[p].x + (float)A1[p].x + (float)A2[p].x + bv;
                float hi = (float)A0[p].y + (float)A1[p].y + (float)A2[p].y + bv;
                f16x2 hp = { (f16)lo, (f16)hi };
                ow[p] = hAsU(hp);
            }
            *(uint4*)(outb + (size_t)(ch0 + c) * 512 + dh * 8) = make_uint4(ow[0], ow[1], ow[2], ow[3]);
        }
    }
}

// ---------------------------------------------------------------------------
// K3 v11 = v7 + s_setprio(1) around the QK and PV MFMA clusters (T5: waves
// run phase-shifted independent loops -> scheduler favors the MFMA-ready
// wave). Everything else identical to v7.
// ---------------------------------------------------------------------------
__global__ __launch_bounds__(512) void k3_attn(
    const f16* __restrict__ qF, const f16* __restrict__ kF, const f16* __restrict__ vF,
    float* __restrict__ outp)
{
    __shared__ __align__(16) f16 Ksh[512 * 104];   // 106496 B
    __shared__ __align__(16) f16 Psh[8 * 1152];    // 8 waves x [16 q][72 k]

    const int tid = threadIdx.x;
    const int b = blockIdx.x;
    const int wv_ = tid >> 6, lane = tid & 63, lr = lane & 15, lk = lane >> 4;

    const f16* qg = qF + ((size_t)b * 512 + wv_ * 64) * 96;
    const f16* kg = kF + (size_t)b * 512 * 96;
    const f16* vg = vF + (size_t)b * 96 * 512;

    const float scl = 0.14724447f;   // log2(e)/sqrt(96), applied post-MFMA

    #pragma unroll
    for (int it = 0; it < 12; ++it) {
        int i = tid * 8 + it * 4096;
        int r = i / 96, c = i % 96;
        *(uint4*)(Ksh + r * 104 + c) = *(const uint4*)(kg + i);
    }
    __syncthreads();

    float sum_p[4] = {0.f, 0.f, 0.f, 0.f};
    f32x4 accO[4][6];
    #pragma unroll
    for (int qg2 = 0; qg2 < 4; ++qg2)
        #pragma unroll
        for (int cg = 0; cg < 6; ++cg) accO[qg2][cg] = f32x4{0.f, 0.f, 0.f, 0.f};

    f16* psw = Psh + wv_ * 1152;
    uint2* psw2 = (uint2*)psw;

    for (int t = 0; t < 8; ++t) {
        f16x8 kf[3][4];
        #pragma unroll
        for (int ks3 = 0; ks3 < 3; ++ks3)
            #pragma unroll
            for (int f = 0; f < 4; ++f)
                kf[ks3][f] = *(const f16x8*)(Ksh + (t * 64 + f * 16 + lr) * 104 + ks3 * 32 + lk * 8);
        f16x8 vb[2][6];
        #pragma unroll
        for (int ks2 = 0; ks2 < 2; ++ks2)
            #pragma unroll
            for (int cg = 0; cg < 6; ++cg)
                vb[ks2][cg] = *(const f16x8*)(vg + (size_t)(cg * 16 + lr) * 512
                                                 + t * 64 + ks2 * 32 + lk * 8);
        #pragma unroll
        for (int qg2 = 0; qg2 < 4; ++qg2) {
            f16x8 qf3[3];
            #pragma unroll
            for (int ks3 = 0; ks3 < 3; ++ks3)
                qf3[ks3] = *(const f16x8*)(qg + (qg2 * 16 + lr) * 96 + ks3 * 32 + lk * 8);
            f32x4 sa[4];
            #pragma unroll
            for (int f = 0; f < 4; ++f) sa[f] = f32x4{0.f, 0.f, 0.f, 0.f};
            __builtin_amdgcn_s_setprio(1);
            #pragma unroll
            for (int ks3 = 0; ks3 < 3; ++ks3)
                #pragma unroll
                for (int f = 0; f < 4; ++f)
                    sa[f] = __builtin_amdgcn_mfma_f32_16x16x32_f16(kf[ks3][f], qf3[ks3], sa[f], 0, 0, 0);
            __builtin_amdgcn_s_setprio(0);
            #pragma unroll
            for (int f = 0; f < 4; ++f) {
                float e0 = __builtin_amdgcn_exp2f(sa[f][0] * scl);
                float e1 = __builtin_amdgcn_exp2f(sa[f][1] * scl);
                float e2 = __builtin_amdgcn_exp2f(sa[f][2] * scl);
                float e3 = __builtin_amdgcn_exp2f(sa[f][3] * scl);
                sum_p[qg2] += (e0 + e1) + (e2 + e3);
                uint2 pk;
                pk.x = pAsU(__builtin_amdgcn_cvt_pkrtz(e0, e1));
                pk.y = pAsU(__builtin_amdgcn_cvt_pkrtz(e2, e3));
                psw2[lr * 18 + f * 4 + lk] = pk;
            }
            __builtin_amdgcn_s_setprio(1);
            #pragma unroll
            for (int ks2 = 0; ks2 < 2; ++ks2) {
                f16x8 pb = *(const f16x8*)(psw + lr * 72 + ks2 * 32 + lk * 8);
                #pragma unroll
                for (int cg = 0; cg < 6; ++cg)
                    accO[qg2][cg] = __builtin_amdgcn_mfma_f32_16x16x32_f16(
                        vb[ks2][cg], pb, accO[qg2][cg], 0, 0, 0);
            }
            __builtin_amdgcn_s_setprio(0);
        }
    }
    #pragma unroll
    for (int qg2 = 0; qg2 < 4; ++qg2) {
        sum_p[qg2] += __shfl_xor(sum_p[qg2], 16);
        sum_p[qg2] += __shfl_xor(sum_p[qg2], 32);
    }

    #pragma unroll
    for (int qg2 = 0; qg2 < 4; ++qg2) {
        const float inv = 1.0f / sum_p[qg2];
        float* og = outp + ((size_t)b * 512 + wv_ * 64 + qg2 * 16 + lr) * 96;
        #pragma unroll
        for (int cg = 0; cg < 6; ++cg) {
            float4 o4 = make_float4(accO[qg2][cg][0] * inv, accO[qg2][cg][1] * inv,
                                    accO[qg2][cg][2] * inv, accO[qg2][cg][3] * inv);
            *(float4*)(og + cg * 16 + lk * 4) = o4;
        }
    }
}

extern "C" void kernel_launch(void* const* d_in, const int* in_sizes, int n_in,
                              void* d_out, int out_size, void* d_ws, size_t ws_size,
                              hipStream_t stream) {
    const float* x   = (const float*)d_in[0];
    const float* wq1 = (const float*)d_in[1];
    const float* bq1 = (const float*)d_in[2];
    const float* wk1 = (const float*)d_in[3];
    const float* bk1 = (const float*)d_in[4];
    const float* wv1 = (const float*)d_in[5];
    const float* bv1 = (const float*)d_in[6];
    const float* wqd = (const float*)d_in[7];
    const float* bqd = (const float*)d_in[8];
    const float* wkd = (const float*)d_in[9];
    const float* bkd = (const float*)d_in[10];
    const float* wvd = (const float*)d_in[11];
    const float* bvd = (const float*)d_in[12];

    f16* ws = (f16*)d_ws;
    f16* q  = ws;
    f16* k  = ws + PL;
    f16* v  = ws + 2 * PL;
    f16* xh = ws + 3 * PL;

    kcvt<<<3072, 256, 0, stream>>>(x, xh);
    k12_fused<<<3072, 512, 0, stream>>>(xh, wq1, bq1, wk1, bk1, wv1, bv1,
                                        wqd, bqd, wkd, bkd, wvd, bvd, q, k, v);
    k3_attn<<<512, 512, 0, stream>>>(q, k, v, (float*)d_out);
}

// Round 23
// 243.209 us; speedup vs baseline: 1.2783x; 1.2783x over previous
//
#include <hip/hip_runtime.h>
#include <math.h>

typedef _Float16 f16;
typedef _Float16 f16x2 __attribute__((ext_vector_type(2)));
typedef _Float16 f16x8 __attribute__((ext_vector_type(8)));
typedef __fp16 fp16x2 __attribute__((ext_vector_type(2)));
typedef float f32x4 __attribute__((ext_vector_type(4)));

union F2U { f16x2 h; fp16x2 p; unsigned u; };
union U2H { uint2 q; f16x2 h[2]; f16 f[4]; };
union U4H { uint4 q; f16x2 h[4]; f16 f[8]; };
union V8H { f16x8 v; f16x2 h[4]; f16 f[8]; uint4 q; };

__device__ __forceinline__ f16x2 uAsH(unsigned u) { F2U c; c.u = u; return c.h; }
__device__ __forceinline__ unsigned hAsU(f16x2 h) { F2U c; c.h = h; return c.u; }
__device__ __forceinline__ unsigned pAsU(fp16x2 p) { F2U c; c.p = p; return c.u; }

__device__ __forceinline__ f16x8 ld8cvt(const float* p) {
    float4 a = *(const float4*)p;
    float4 b = *(const float4*)(p + 4);
    V8H r;
    r.f[0] = (f16)a.x; r.f[1] = (f16)a.y; r.f[2] = (f16)a.z; r.f[3] = (f16)a.w;
    r.f[4] = (f16)b.x; r.f[5] = (f16)b.y; r.f[6] = (f16)b.z; r.f[7] = (f16)b.w;
    return r.v;
}

constexpr size_t PL = (size_t)512 * 512 * 96;

// ---------------------------------------------------------------------------
// K0: x f32 -> f16 (one pass; xh is L3-resident for k12's 6x re-reads).
// ---------------------------------------------------------------------------
__global__ __launch_bounds__(256) void kcvt(const float* __restrict__ x,
                                            f16* __restrict__ xh)
{
    const int id = blockIdx.x * 256 + threadIdx.x;   // 786432 threads
    #pragma unroll
    for (int it = 0; it < 4; ++it) {
        size_t i = ((size_t)id + (size_t)it * 786432) * 8;
        V8H r; r.v = ld8cvt(x + i);
        *(uint4*)(xh + i) = r.q;
    }
}

// ---------------------------------------------------------------------------
// K12 v11 (record config, 116 us): channel-split fused pointwise+depthwise
// reading pre-converted f16 xh. 1-D grid 3072, batch-major decode. block 512.
// Outputs: q,k [b][n][c]; v [b][c][n].
// ---------------------------------------------------------------------------
__global__ __launch_bounds__(512) void k12_fused(
    const f16* __restrict__ xh,
    const float* __restrict__ wq1, const float* __restrict__ bq1,
    const float* __restrict__ wk1, const float* __restrict__ bk1,
    const float* __restrict__ wv1, const float* __restrict__ bv1,
    const float* __restrict__ wqd, const float* __restrict__ bqd,
    const float* __restrict__ wkd, const float* __restrict__ bkd,
    const float* __restrict__ wvd, const float* __restrict__ bvd,
    f16* __restrict__ qo, f16* __restrict__ ko, f16* __restrict__ vo)
{
    __shared__ __align__(16) char sm[74400];

    const int tid = threadIdx.x;
    const int id = blockIdx.x;
    const int b = id / 6;
    const int r6 = id - b * 6;
    const int which = r6 >> 1;
    const int chalf = r6 & 1;
    const int ch0 = chalf * 48;
    const int wv_ = tid >> 6, lane = tid & 63, lr = lane & 15, lk = lane >> 4;

    const float* w1 = (which == 0) ? wq1 : ((which == 1) ? wk1 : wv1);
    const float* b1 = (which == 0) ? bq1 : ((which == 1) ? bk1 : bv1);
    const float* wd = (which == 0) ? wqd : ((which == 1) ? wkd : wvd);
    const float* bd = (which == 0) ? bqd : ((which == 1) ? bkd : bvd);
    const f16* xb = xh + (size_t)b * 512 * 96;

    if (which < 2) {
        f16*      slab = (f16*)sm;                 // [512][60] GEMM out
        f16*      Wsh  = (f16*)(sm + 61440);       // [48][104] pointwise w
        unsigned* wdh  = (unsigned*)(sm + 71424);  // [27][24] u32
        float*    bl1  = (float*)(sm + 74016);
        float*    bld  = (float*)(sm + 74208);

        #pragma unroll
        for (int it = 0; it < 3; ++it) {
            int g = tid + it * 512;
            if (g < 1152) {
                int i = g * 4;
                int co = i / 96, ci = i % 96;
                float4 v4 = *(const float4*)(w1 + (size_t)(ch0 + co) * 96 + ci);
                f16x2 h01 = { (f16)v4.x, (f16)v4.y };
                f16x2 h23 = { (f16)v4.z, (f16)v4.w };
                uint2 st; st.x = hAsU(h01); st.y = hAsU(h23);
                *(uint2*)(Wsh + co * 104 + ci) = st;
            }
        }
        for (int ii = tid; ii < 1296; ii += 512) {
            int lc = ii / 27, t2 = ii % 27;
            ((f16*)wdh)[t2 * 48 + lc] = (f16)wd[(ch0 + lc) * 27 + t2];
        }
        if (tid < 48) { bl1[tid] = b1[ch0 + tid]; bld[tid] = bd[ch0 + tid]; }
        __syncthreads();

        f32x4 acc[4][3];
        #pragma unroll
        for (int pg = 0; pg < 4; ++pg)
            #pragma unroll
            for (int cg = 0; cg < 3; ++cg) acc[pg][cg] = f32x4{0.f, 0.f, 0.f, 0.f};
        #pragma unroll
        for (int ks = 0; ks < 3; ++ks) {
            f16x8 bfr[3];
            #pragma unroll
            for (int cg = 0; cg < 3; ++cg)
                bfr[cg] = *(const f16x8*)(Wsh + (cg * 16 + lr) * 104 + ks * 32 + lk * 8);
            #pragma unroll
            for (int pg = 0; pg < 4; ++pg) {
                f16x8 a = *(const f16x8*)(xb + (size_t)(wv_ * 64 + pg * 16 + lr) * 96 + ks * 32 + lk * 8);
                #pragma unroll
                for (int cg = 0; cg < 3; ++cg)
                    acc[pg][cg] = __builtin_amdgcn_mfma_f32_16x16x32_f16(bfr[cg], a, acc[pg][cg], 0, 0, 0);
            }
        }
        __syncthreads();

        #pragma unroll
        for (int pg = 0; pg < 4; ++pg) {
            int pos = wv_ * 64 + pg * 16 + lr;
            #pragma unroll
            for (int cg = 0; cg < 3; ++cg) {
                float4 bv4 = *(const float4*)&bl1[cg * 16 + lk * 4];
                f16x2 h01 = { (f16)(acc[pg][cg][0] + bv4.x), (f16)(acc[pg][cg][1] + bv4.y) };
                f16x2 h23 = { (f16)(acc[pg][cg][2] + bv4.z), (f16)(acc[pg][cg][3] + bv4.w) };
                uint2 st; st.x = hAsU(h01); st.y = hAsU(h23);
                *(uint2*)(slab + pos * 60 + cg * 16 + lk * 4) = st;
            }
        }
        __syncthreads();

        f16* outb = ((which == 0) ? qo : ko) + (size_t)b * 512 * 96;
        #pragma unroll
        for (int half = 0; half < 2; ++half) {
            if (half == 1 && tid >= 256) break;
            const int u = half * 512 + tid;
            const int r = u / 12;
            const int g4 = u - r * 12;
            const int dd = r >> 3, hh = r & 7;
            const int col = g4 * 4;
            float mo[8][4];
            {
                float4 b0 = *(const float4*)&bld[col];
                #pragma unroll
                for (int w = 0; w < 8; ++w) {
                    mo[w][0] = b0.x; mo[w][1] = b0.y; mo[w][2] = b0.z; mo[w][3] = b0.w;
                }
            }
            #pragma unroll
            for (int kd = 0; kd < 3; ++kd) {
                const int d2 = dd + kd - 1;
                const bool vd = (unsigned)d2 < 8u;
                f16x2 pa[8][2];
                #pragma unroll
                for (int w = 0; w < 8; ++w) {
                    pa[w][0] = f16x2{0, 0}; pa[w][1] = f16x2{0, 0};
                }
                #pragma unroll
                for (int kh = 0; kh < 3; ++kh) {
                    const int h2 = hh + kh - 1;
                    const unsigned vm = (vd && ((unsigned)h2 < 8u)) ? 0xFFFFFFFFu : 0u;
                    const int base = (vm ? (d2 * 64 + h2 * 8) : 0) * 60 + col;
                    U2H in[8];
                    #pragma unroll
                    for (int w2 = 0; w2 < 8; ++w2)
                        in[w2].q = *(const uint2*)(slab + base + w2 * 60);
                    const int t0 = (kd * 3 + kh) * 3;
                    f16x2 wt0[2], wt1[2], wt2[2];
                    #pragma unroll
                    for (int p = 0; p < 2; ++p) {
                        wt0[p] = uAsH(wdh[(t0 + 0) * 24 + g4 * 2 + p] & vm);
                        wt1[p] = uAsH(wdh[(t0 + 1) * 24 + g4 * 2 + p] & vm);
                        wt2[p] = uAsH(wdh[(t0 + 2) * 24 + g4 * 2 + p] & vm);
                    }
                    #pragma unroll
                    for (int w = 0; w < 8; ++w) {
                        #pragma unroll
                        for (int p = 0; p < 2; ++p) {
                            f16x2 s = pa[w][p];
                            s = in[w].h[p] * wt1[p] + s;
                            if (w > 0) s = in[w - 1].h[p] * wt0[p] + s;
                            if (w < 7) s = in[w + 1].h[p] * wt2[p] + s;
                            pa[w][p] = s;
                        }
                    }
                }
                #pragma unroll
                for (int w = 0; w < 8; ++w)
                    #pragma unroll
                    for (int p = 0; p < 2; ++p) {
                        mo[w][2 * p]     += (float)pa[w][p].x;
                        mo[w][2 * p + 1] += (float)pa[w][p].y;
                    }
            }
            #pragma unroll
            for (int w = 0; w < 8; ++w) {
                f16x2 h0 = { (f16)mo[w][0], (f16)mo[w][1] };
                f16x2 h1 = { (f16)mo[w][2], (f16)mo[w][3] };
                uint2 st; st.x = hAsU(h0); st.y = hAsU(h1);
                *(uint2*)(outb + (size_t)(r * 8 + w) * 96 + ch0 + col) = st;
            }
        }
    } else {
        f16*      Vsh = (f16*)sm;                  // [48][520] GEMM out
        f16*      Wsh = (f16*)(sm + 49920);        // [48][104]
        unsigned* wdp = (unsigned*)(sm + 59904);   // [48][27]
        float*    bl1 = (float*)(sm + 65088);
        float*    bld = (float*)(sm + 65280);

        #pragma unroll
        for (int it = 0; it < 3; ++it) {
            int g = tid + it * 512;
            if (g < 1152) {
                int i = g * 4;
                int co = i / 96, ci = i % 96;
                float4 v4 = *(const float4*)(w1 + (size_t)(ch0 + co) * 96 + ci);
                f16x2 h01 = { (f16)v4.x, (f16)v4.y };
                f16x2 h23 = { (f16)v4.z, (f16)v4.w };
                uint2 st; st.x = hAsU(h01); st.y = hAsU(h23);
                *(uint2*)(Wsh + co * 104 + ci) = st;
            }
        }
        for (int ii = tid; ii < 1296; ii += 512) {
            int lc = ii / 27, t2 = ii % 27;
            f16 hh = (f16)wd[(ch0 + lc) * 27 + t2];
            f16x2 hp = { hh, hh };
            wdp[lc * 27 + t2] = hAsU(hp);
        }
        if (tid < 48) { bl1[tid] = b1[ch0 + tid]; bld[tid] = bd[ch0 + tid]; }
        __syncthreads();

        f32x4 acc[4][3];
        #pragma unroll
        for (int pg = 0; pg < 4; ++pg)
            #pragma unroll
            for (int cg = 0; cg < 3; ++cg) acc[pg][cg] = f32x4{0.f, 0.f, 0.f, 0.f};
        #pragma unroll
        for (int ks = 0; ks < 3; ++ks) {
            f16x8 bfr[3];
            #pragma unroll
            for (int cg = 0; cg < 3; ++cg)
                bfr[cg] = *(const f16x8*)(Wsh + (cg * 16 + lr) * 104 + ks * 32 + lk * 8);
            #pragma unroll
            for (int pg = 0; pg < 4; ++pg) {
                f16x8 a = *(const f16x8*)(xb + (size_t)(wv_ * 64 + pg * 16 + lr) * 96 + ks * 32 + lk * 8);
                #pragma unroll
                for (int cg = 0; cg < 3; ++cg)
                    acc[pg][cg] = __builtin_amdgcn_mfma_f32_16x16x32_f16(a, bfr[cg], acc[pg][cg], 0, 0, 0);
            }
        }
        __syncthreads();

        #pragma unroll
        for (int pg = 0; pg < 4; ++pg) {
            int pos = wv_ * 64 + pg * 16 + lk * 4;
            #pragma unroll
            for (int cg = 0; cg < 3; ++cg) {
                float bv = bl1[cg * 16 + lr];
                int lc = cg * 16 + lr;
                f16x2 h01 = { (f16)(acc[pg][cg][0] + bv), (f16)(acc[pg][cg][1] + bv) };
                f16x2 h23 = { (f16)(acc[pg][cg][2] + bv), (f16)(acc[pg][cg][3] + bv) };
                uint2 st; st.x = hAsU(h01); st.y = hAsU(h23);
                *(uint2*)(Vsh + lc * 520 + pos) = st;
            }
        }
        __syncthreads();

        f16* outb = vo + (size_t)b * 96 * 512;
        #pragma unroll
        for (int j = 0; j < 6; ++j) {
            int u = tid + j * 512;
            int c = u >> 6, dh = u & 63;
            int dd = dh >> 3, hh2 = dh & 7;
            f16x2 A0[4], A1[4], A2[4];
            #pragma unroll
            for (int p = 0; p < 4; ++p) {
                A0[p] = f16x2{0, 0}; A1[p] = f16x2{0, 0}; A2[p] = f16x2{0, 0};
            }
            #pragma unroll
            for (int kd = 0; kd < 3; ++kd) {
                int d2 = dd + kd - 1;
                unsigned vd_ = ((unsigned)d2 < 8u) ? 0xFFFFFFFFu : 0u;
                #pragma unroll
                for (int kh = 0; kh < 3; ++kh) {
                    int h2 = hh2 + kh - 1;
                    unsigned vm = ((((unsigned)h2 < 8u) ? 0xFFFFFFFFu : 0u) & vd_);
                    int rowoff = vm ? ((d2 * 8 + h2) * 8) : 0;
                    uint4 rw = *(const uint4*)(Vsh + c * 520 + rowoff);
                    unsigned r0 = rw.x, r1 = rw.y, r2 = rw.z, r3 = rw.w;
                    unsigned ms0 = r0 << 16;
                    unsigned ms1 = (r1 << 16) | (r0 >> 16);
                    unsigned ms2 = (r2 << 16) | (r1 >> 16);
                    unsigned ms3 = (r3 << 16) | (r2 >> 16);
                    unsigned ms4 = r3 >> 16;
                    int t0 = kd * 9 + kh * 3;
                    f16x2 w0 = uAsH(wdp[c * 27 + t0]     & vm);
                    f16x2 w1 = uAsH(wdp[c * 27 + t0 + 1] & vm);
                    f16x2 w2 = uAsH(wdp[c * 27 + t0 + 2] & vm);
                    f16x2* acc2 = (kd == 0) ? A0 : ((kd == 1) ? A1 : A2);
                    acc2[0] = uAsH(ms0) * w0 + acc2[0];
                    acc2[1] = uAsH(ms1) * w0 + acc2[1];
                    acc2[2] = uAsH(ms2) * w0 + acc2[2];
                    acc2[3] = uAsH(ms3) * w0 + acc2[3];
                    acc2[0] = uAsH(r0) * w1 + acc2[0];
                    acc2[1] = uAsH(r1) * w1 + acc2[1];
                    acc2[2] = uAsH(r2) * w1 + acc2[2];
                    acc2[3] = uAsH(r3) * w1 + acc2[3];
                    acc2[0] = uAsH(ms1) * w2 + acc2[0];
                    acc2[1] = uAsH(ms2) * w2 + acc2[1];
                    acc2[2] = uAsH(ms3) * w2 + acc2[2];
                    acc2[3] = uAsH(ms4) * w2 + acc2[3];
                }
            }
            float bv = bld[c];
            unsigned ow[4];
            #pragma unroll
            for (int p = 0; p < 4; ++p) {
                float lo = (float)A0[p].x + (float)A1[p].x + (float)A2[p].x + bv;
                float hi = (float)A0[p].y + (float)A1[p].y + (float)A2[p].y + bv;
                f16x2 hp = { (f16)lo, (f16)hi };
                ow[p] = hAsU(hp);
            }
            *(uint4*)(outb + (size_t)(ch0 + c) * 512 + dh * 8) = make_uint4(ow[0], ow[1], ow[2], ow[3]);
        }
    }
}

// ---------------------------------------------------------------------------
// K3 v7 (record config): single-pass softmax, kf + vb hoisted per tile,
// qf streamed per q-group, 512 threads (8 waves x 64 q-rows). grid 512.
// ---------------------------------------------------------------------------
__global__ __launch_bounds__(512) void k3_attn(
    const f16* __restrict__ qF, const f16* __restrict__ kF, const f16* __restrict__ vF,
    float* __restrict__ outp)
{
    __shared__ __align__(16) f16 Ksh[512 * 104];   // 106496 B
    __shared__ __align__(16) f16 Psh[8 * 1152];    // 8 waves x [16 q][72 k]

    const int tid = threadIdx.x;
    const int b = blockIdx.x;
    const int wv_ = tid >> 6, lane = tid & 63, lr = lane & 15, lk = lane >> 4;

    const f16* qg = qF + ((size_t)b * 512 + wv_ * 64) * 96;
    const f16* kg = kF + (size_t)b * 512 * 96;
    const f16* vg = vF + (size_t)b * 96 * 512;

    const float scl = 0.14724447f;   // log2(e)/sqrt(96), applied post-MFMA

    #pragma unroll
    for (int it = 0; it < 12; ++it) {
        int i = tid * 8 + it * 4096;
        int r = i / 96, c = i % 96;
        *(uint4*)(Ksh + r * 104 + c) = *(const uint4*)(kg + i);
    }
    __syncthreads();

    float sum_p[4] = {0.f, 0.f, 0.f, 0.f};
    f32x4 accO[4][6];
    #pragma unroll
    for (int qg2 = 0; qg2 < 4; ++qg2)
        #pragma unroll
        for (int cg = 0; cg < 6; ++cg) accO[qg2][cg] = f32x4{0.f, 0.f, 0.f, 0.f};

    f16* psw = Psh + wv_ * 1152;
    uint2* psw2 = (uint2*)psw;

    for (int t = 0; t < 8; ++t) {
        f16x8 kf[3][4];
        #pragma unroll
        for (int ks3 = 0; ks3 < 3; ++ks3)
            #pragma unroll
            for (int f = 0; f < 4; ++f)
                kf[ks3][f] = *(const f16x8*)(Ksh + (t * 64 + f * 16 + lr) * 104 + ks3 * 32 + lk * 8);
        f16x8 vb[2][6];
        #pragma unroll
        for (int ks2 = 0; ks2 < 2; ++ks2)
            #pragma unroll
            for (int cg = 0; cg < 6; ++cg)
                vb[ks2][cg] = *(const f16x8*)(vg + (size_t)(cg * 16 + lr) * 512
                                                 + t * 64 + ks2 * 32 + lk * 8);
        #pragma unroll
        for (int qg2 = 0; qg2 < 4; ++qg2) {
            f16x8 qf3[3];
            #pragma unroll
            for (int ks3 = 0; ks3 < 3; ++ks3)
                qf3[ks3] = *(const f16x8*)(qg + (qg2 * 16 + lr) * 96 + ks3 * 32 + lk * 8);
            f32x4 sa[4];
            #pragma unroll
            for (int f = 0; f < 4; ++f) sa[f] = f32x4{0.f, 0.f, 0.f, 0.f};
            #pragma unroll
            for (int ks3 = 0; ks3 < 3; ++ks3)
                #pragma unroll
                for (int f = 0; f < 4; ++f)
                    sa[f] = __builtin_amdgcn_mfma_f32_16x16x32_f16(kf[ks3][f], qf3[ks3], sa[f], 0, 0, 0);
            #pragma unroll
            for (int f = 0; f < 4; ++f) {
                float e0 = __builtin_amdgcn_exp2f(sa[f][0] * scl);
                float e1 = __builtin_amdgcn_exp2f(sa[f][1] * scl);
                float e2 = __builtin_amdgcn_exp2f(sa[f][2] * scl);
                float e3 = __builtin_amdgcn_exp2f(sa[f][3] * scl);
                sum_p[qg2] += (e0 + e1) + (e2 + e3);
                uint2 pk;
                pk.x = pAsU(__builtin_amdgcn_cvt_pkrtz(e0, e1));
                pk.y = pAsU(__builtin_amdgcn_cvt_pkrtz(e2, e3));
                psw2[lr * 18 + f * 4 + lk] = pk;
            }
            #pragma unroll
            for (int ks2 = 0; ks2 < 2; ++ks2) {
                f16x8 pb = *(const f16x8*)(psw + lr * 72 + ks2 * 32 + lk * 8);
                #pragma unroll
                for (int cg = 0; cg < 6; ++cg)
                    accO[qg2][cg] = __builtin_amdgcn_mfma_f32_16x16x32_f16(
                        vb[ks2][cg], pb, accO[qg2][cg], 0, 0, 0);
            }
        }
    }
    #pragma unroll
    for (int qg2 = 0; qg2 < 4; ++qg2) {
        sum_p[qg2] += __shfl_xor(sum_p[qg2], 16);
        sum_p[qg2] += __shfl_xor(sum_p[qg2], 32);
    }

    #pragma unroll
    for (int qg2 = 0; qg2 < 4; ++qg2) {
        const float inv = 1.0f / sum_p[qg2];
        float* og = outp + ((size_t)b * 512 + wv_ * 64 + qg2 * 16 + lr) * 96;
        #pragma unroll
        for (int cg = 0; cg < 6; ++cg) {
            float4 o4 = make_float4(accO[qg2][cg][0] * inv, accO[qg2][cg][1] * inv,
                                    accO[qg2][cg][2] * inv, accO[qg2][cg][3] * inv);
            *(float4*)(og + cg * 16 + lk * 4) = o4;
        }
    }
}

extern "C" void kernel_launch(void* const* d_in, const int* in_sizes, int n_in,
                              void* d_out, int out_size, void* d_ws, size_t ws_size,
                              hipStream_t stream) {
    const float* x   = (const float*)d_in[0];
    const float* wq1 = (const float*)d_in[1];
    const float* bq1 = (const float*)d_in[2];
    const float* wk1 = (const float*)d_in[3];
    const float* bk1 = (const float*)d_in[4];
    const float* wv1 = (const float*)d_in[5];
    const float* bv1 = (const float*)d_in[6];
    const float* wqd = (const float*)d_in[7];
    const float* bqd = (const float*)d_in[8];
    const float* wkd = (const float*)d_in[9];
    const float* bkd = (const float*)d_in[10];
    const float* wvd = (const float*)d_in[11];
    const float* bvd = (const float*)d_in[12];

    f16* ws = (f16*)d_ws;
    f16* q  = ws;
    f16* k  = ws + PL;
    f16* v  = ws + 2 * PL;
    f16* xh = ws + 3 * PL;

    kcvt<<<3072, 256, 0, stream>>>(x, xh);
    k12_fused<<<3072, 512, 0, stream>>>(xh, wq1, bq1, wk1, bk1, wv1, bv1,
                                        wqd, bqd, wkd, bkd, wvd, bvd, q, k, v);
    k3_attn<<<512, 512, 0, stream>>>(q, k, v, (float*)d_out);
}

// Round 24
// 228.184 us; speedup vs baseline: 1.3625x; 1.0658x over previous
//
#include <hip/hip_runtime.h>
#include <math.h>

typedef _Float16 f16;
typedef _Float16 f16x2 __attribute__((ext_vector_type(2)));
typedef _Float16 f16x8 __attribute__((ext_vector_type(8)));
typedef __fp16 fp16x2 __attribute__((ext_vector_type(2)));
typedef float f32x4 __attribute__((ext_vector_type(4)));

union F2U { f16x2 h; fp16x2 p; unsigned u; };
union U2H { uint2 q; f16x2 h[2]; f16 f[4]; };
union U4H { uint4 q; f16x2 h[4]; f16 f[8]; };
union V8H { f16x8 v; f16x2 h[4]; f16 f[8]; uint4 q; };

__device__ __forceinline__ f16x2 uAsH(unsigned u) { F2U c; c.u = u; return c.h; }
__device__ __forceinline__ unsigned hAsU(f16x2 h) { F2U c; c.h = h; return c.u; }
__device__ __forceinline__ unsigned pAsU(fp16x2 p) { F2U c; c.p = p; return c.u; }

__device__ __forceinline__ f16x8 ld8cvt(const float* p) {
    float4 a = *(const float4*)p;
    float4 b = *(const float4*)(p + 4);
    V8H r;
    r.f[0] = (f16)a.x; r.f[1] = (f16)a.y; r.f[2] = (f16)a.z; r.f[3] = (f16)a.w;
    r.f[4] = (f16)b.x; r.f[5] = (f16)b.y; r.f[6] = (f16)b.z; r.f[7] = (f16)b.w;
    return r.v;
}

constexpr size_t PL = (size_t)512 * 512 * 96;

// ---------------------------------------------------------------------------
// K0: x f32 -> f16 (one pass; xh is cache-resident for k12's re-reads).
// ---------------------------------------------------------------------------
__global__ __launch_bounds__(256) void kcvt(const float* __restrict__ x,
                                            f16* __restrict__ xh)
{
    const int id = blockIdx.x * 256 + threadIdx.x;   // 786432 threads
    #pragma unroll
    for (int it = 0; it < 4; ++it) {
        size_t i = ((size_t)id + (size_t)it * 786432) * 8;
        V8H r; r.v = ld8cvt(x + i);
        *(uint4*)(xh + i) = r.q;
    }
}

// ---------------------------------------------------------------------------
// K12 v12: v11 body + XCD-affine decode. All 6 blocks of a batch share
// id % 8 (same XCD per the %8 round-robin mapping) and consecutive slots,
// so xh[b] (98 KB) stays in that XCD's private L2 for members 2..6.
// grid 3072, block 512. Outputs: q,k [b][n][c]; v [b][c][n].
// ---------------------------------------------------------------------------
__global__ __launch_bounds__(512) void k12_fused(
    const f16* __restrict__ xh,
    const float* __restrict__ wq1, const float* __restrict__ bq1,
    const float* __restrict__ wk1, const float* __restrict__ bk1,
    const float* __restrict__ wv1, const float* __restrict__ bv1,
    const float* __restrict__ wqd, const float* __restrict__ bqd,
    const float* __restrict__ wkd, const float* __restrict__ bkd,
    const float* __restrict__ wvd, const float* __restrict__ bvd,
    f16* __restrict__ qo, f16* __restrict__ ko, f16* __restrict__ vo)
{
    __shared__ __align__(16) char sm[74400];

    const int tid = threadIdx.x;
    const int id = blockIdx.x;
    // XCD-affine decode: xcd = id&7 (stays fixed for a batch's 6 members)
    const int xcd = id & 7;
    const int s = id >> 3;            // 0..383
    const int j = s % 6;              // member: which*2 + chalf
    const int bg = s / 6;             // 0..63
    const int b = bg * 8 + xcd;
    const int which = j >> 1;
    const int chalf = j & 1;
    const int ch0 = chalf * 48;
    const int wv_ = tid >> 6, lane = tid & 63, lr = lane & 15, lk = lane >> 4;

    const float* w1 = (which == 0) ? wq1 : ((which == 1) ? wk1 : wv1);
    const float* b1 = (which == 0) ? bq1 : ((which == 1) ? bk1 : bv1);
    const float* wd = (which == 0) ? wqd : ((which == 1) ? wkd : wvd);
    const float* bd = (which == 0) ? bqd : ((which == 1) ? bkd : bvd);
    const f16* xb = xh + (size_t)b * 512 * 96;

    if (which < 2) {
        f16*      slab = (f16*)sm;                 // [512][60] GEMM out
        f16*      Wsh  = (f16*)(sm + 61440);       // [48][104] pointwise w
        unsigned* wdh  = (unsigned*)(sm + 71424);  // [27][24] u32
        float*    bl1  = (float*)(sm + 74016);
        float*    bld  = (float*)(sm + 74208);

        #pragma unroll
        for (int it = 0; it < 3; ++it) {
            int g = tid + it * 512;
            if (g < 1152) {
                int i = g * 4;
                int co = i / 96, ci = i % 96;
                float4 v4 = *(const float4*)(w1 + (size_t)(ch0 + co) * 96 + ci);
                f16x2 h01 = { (f16)v4.x, (f16)v4.y };
                f16x2 h23 = { (f16)v4.z, (f16)v4.w };
                uint2 st; st.x = hAsU(h01); st.y = hAsU(h23);
                *(uint2*)(Wsh + co * 104 + ci) = st;
            }
        }
        for (int ii = tid; ii < 1296; ii += 512) {
            int lc = ii / 27, t2 = ii % 27;
            ((f16*)wdh)[t2 * 48 + lc] = (f16)wd[(ch0 + lc) * 27 + t2];
        }
        if (tid < 48) { bl1[tid] = b1[ch0 + tid]; bld[tid] = bd[ch0 + tid]; }
        __syncthreads();

        f32x4 acc[4][3];
        #pragma unroll
        for (int pg = 0; pg < 4; ++pg)
            #pragma unroll
            for (int cg = 0; cg < 3; ++cg) acc[pg][cg] = f32x4{0.f, 0.f, 0.f, 0.f};
        #pragma unroll
        for (int ks = 0; ks < 3; ++ks) {
            f16x8 bfr[3];
            #pragma unroll
            for (int cg = 0; cg < 3; ++cg)
                bfr[cg] = *(const f16x8*)(Wsh + (cg * 16 + lr) * 104 + ks * 32 + lk * 8);
            #pragma unroll
            for (int pg = 0; pg < 4; ++pg) {
                f16x8 a = *(const f16x8*)(xb + (size_t)(wv_ * 64 + pg * 16 + lr) * 96 + ks * 32 + lk * 8);
                #pragma unroll
                for (int cg = 0; cg < 3; ++cg)
                    acc[pg][cg] = __builtin_amdgcn_mfma_f32_16x16x32_f16(bfr[cg], a, acc[pg][cg], 0, 0, 0);
            }
        }
        __syncthreads();

        #pragma unroll
        for (int pg = 0; pg < 4; ++pg) {
            int pos = wv_ * 64 + pg * 16 + lr;
            #pragma unroll
            for (int cg = 0; cg < 3; ++cg) {
                float4 bv4 = *(const float4*)&bl1[cg * 16 + lk * 4];
                f16x2 h01 = { (f16)(acc[pg][cg][0] + bv4.x), (f16)(acc[pg][cg][1] + bv4.y) };
                f16x2 h23 = { (f16)(acc[pg][cg][2] + bv4.z), (f16)(acc[pg][cg][3] + bv4.w) };
                uint2 st; st.x = hAsU(h01); st.y = hAsU(h23);
                *(uint2*)(slab + pos * 60 + cg * 16 + lk * 4) = st;
            }
        }
        __syncthreads();

        f16* outb = ((which == 0) ? qo : ko) + (size_t)b * 512 * 96;
        #pragma unroll
        for (int half = 0; half < 2; ++half) {
            if (half == 1 && tid >= 256) break;
            const int u = half * 512 + tid;
            const int r = u / 12;
            const int g4 = u - r * 12;
            const int dd = r >> 3, hh = r & 7;
            const int col = g4 * 4;
            float mo[8][4];
            {
                float4 b0 = *(const float4*)&bld[col];
                #pragma unroll
                for (int w = 0; w < 8; ++w) {
                    mo[w][0] = b0.x; mo[w][1] = b0.y; mo[w][2] = b0.z; mo[w][3] = b0.w;
                }
            }
            #pragma unroll
            for (int kd = 0; kd < 3; ++kd) {
                const int d2 = dd + kd - 1;
                const bool vd = (unsigned)d2 < 8u;
                f16x2 pa[8][2];
                #pragma unroll
                for (int w = 0; w < 8; ++w) {
                    pa[w][0] = f16x2{0, 0}; pa[w][1] = f16x2{0, 0};
                }
                #pragma unroll
                for (int kh = 0; kh < 3; ++kh) {
                    const int h2 = hh + kh - 1;
                    const unsigned vm = (vd && ((unsigned)h2 < 8u)) ? 0xFFFFFFFFu : 0u;
                    const int base = (vm ? (d2 * 64 + h2 * 8) : 0) * 60 + col;
                    U2H in[8];
                    #pragma unroll
                    for (int w2 = 0; w2 < 8; ++w2)
                        in[w2].q = *(const uint2*)(slab + base + w2 * 60);
                    const int t0 = (kd * 3 + kh) * 3;
                    f16x2 wt0[2], wt1[2], wt2[2];
                    #pragma unroll
                    for (int p = 0; p < 2; ++p) {
                        wt0[p] = uAsH(wdh[(t0 + 0) * 24 + g4 * 2 + p] & vm);
                        wt1[p] = uAsH(wdh[(t0 + 1) * 24 + g4 * 2 + p] & vm);
                        wt2[p] = uAsH(wdh[(t0 + 2) * 24 + g4 * 2 + p] & vm);
                    }
                    #pragma unroll
                    for (int w = 0; w < 8; ++w) {
                        #pragma unroll
                        for (int p = 0; p < 2; ++p) {
                            f16x2 s2 = pa[w][p];
                            s2 = in[w].h[p] * wt1[p] + s2;
                            if (w > 0) s2 = in[w - 1].h[p] * wt0[p] + s2;
                            if (w < 7) s2 = in[w + 1].h[p] * wt2[p] + s2;
                            pa[w][p] = s2;
                        }
                    }
                }
                #pragma unroll
                for (int w = 0; w < 8; ++w)
                    #pragma unroll
                    for (int p = 0; p < 2; ++p) {
                        mo[w][2 * p]     += (float)pa[w][p].x;
                        mo[w][2 * p + 1] += (float)pa[w][p].y;
                    }
            }
            #pragma unroll
            for (int w = 0; w < 8; ++w) {
                f16x2 h0 = { (f16)mo[w][0], (f16)mo[w][1] };
                f16x2 h1 = { (f16)mo[w][2], (f16)mo[w][3] };
                uint2 st; st.x = hAsU(h0); st.y = hAsU(h1);
                *(uint2*)(outb + (size_t)(r * 8 + w) * 96 + ch0 + col) = st;
            }
        }
    } else {
        f16*      Vsh = (f16*)sm;                  // [48][520] GEMM out
        f16*      Wsh = (f16*)(sm + 49920);        // [48][104]
        unsigned* wdp = (unsigned*)(sm + 59904);   // [48][27]
        float*    bl1 = (float*)(sm + 65088);
        float*    bld = (float*)(sm + 65280);

        #pragma unroll
        for (int it = 0; it < 3; ++it) {
            int g = tid + it * 512;
            if (g < 1152) {
                int i = g * 4;
                int co = i / 96, ci = i % 96;
                float4 v4 = *(const float4*)(w1 + (size_t)(ch0 + co) * 96 + ci);
                f16x2 h01 = { (f16)v4.x, (f16)v4.y };
                f16x2 h23 = { (f16)v4.z, (f16)v4.w };
                uint2 st; st.x = hAsU(h01); st.y = hAsU(h23);
                *(uint2*)(Wsh + co * 104 + ci) = st;
            }
        }
        for (int ii = tid; ii < 1296; ii += 512) {
            int lc = ii / 27, t2 = ii % 27;
            f16 hh = (f16)wd[(ch0 + lc) * 27 + t2];
            f16x2 hp = { hh, hh };
            wdp[lc * 27 + t2] = hAsU(hp);
        }
        if (tid < 48) { bl1[tid] = b1[ch0 + tid]; bld[tid] = bd[ch0 + tid]; }
        __syncthreads();

        f32x4 acc[4][3];
        #pragma unroll
        for (int pg = 0; pg < 4; ++pg)
            #pragma unroll
            for (int cg = 0; cg < 3; ++cg) acc[pg][cg] = f32x4{0.f, 0.f, 0.f, 0.f};
        #pragma unroll
        for (int ks = 0; ks < 3; ++ks) {
            f16x8 bfr[3];
            #pragma unroll
            for (int cg = 0; cg < 3; ++cg)
                bfr[cg] = *(const f16x8*)(Wsh + (cg * 16 + lr) * 104 + ks * 32 + lk * 8);
            #pragma unroll
            for (int pg = 0; pg < 4; ++pg) {
                f16x8 a = *(const f16x8*)(xb + (size_t)(wv_ * 64 + pg * 16 + lr) * 96 + ks * 32 + lk * 8);
                #pragma unroll
                for (int cg = 0; cg < 3; ++cg)
                    acc[pg][cg] = __builtin_amdgcn_mfma_f32_16x16x32_f16(a, bfr[cg], acc[pg][cg], 0, 0, 0);
            }
        }
        __syncthreads();

        #pragma unroll
        for (int pg = 0; pg < 4; ++pg) {
            int pos = wv_ * 64 + pg * 16 + lk * 4;
            #pragma unroll
            for (int cg = 0; cg < 3; ++cg) {
                float bv = bl1[cg * 16 + lr];
                int lc = cg * 16 + lr;
                f16x2 h01 = { (f16)(acc[pg][cg][0] + bv), (f16)(acc[pg][cg][1] + bv) };
                f16x2 h23 = { (f16)(acc[pg][cg][2] + bv), (f16)(acc[pg][cg][3] + bv) };
                uint2 st; st.x = hAsU(h01); st.y = hAsU(h23);
                *(uint2*)(Vsh + lc * 520 + pos) = st;
            }
        }
        __syncthreads();

        f16* outb = vo + (size_t)b * 96 * 512;
        #pragma unroll
        for (int j2 = 0; j2 < 6; ++j2) {
            int u = tid + j2 * 512;
            int c = u >> 6, dh = u & 63;
            int dd = dh >> 3, hh2 = dh & 7;
            f16x2 A0[4], A1[4], A2[4];
            #pragma unroll
            for (int p = 0; p < 4; ++p) {
                A0[p] = f16x2{0, 0}; A1[p] = f16x2{0, 0}; A2[p] = f16x2{0, 0};
            }
            #pragma unroll
            for (int kd = 0; kd < 3; ++kd) {
                int d2 = dd + kd - 1;
                unsigned vd_ = ((unsigned)d2 < 8u) ? 0xFFFFFFFFu : 0u;
                #pragma unroll
                for (int kh = 0; kh < 3; ++kh) {
                    int h2 = hh2 + kh - 1;
                    unsigned vm = ((((unsigned)h2 < 8u) ? 0xFFFFFFFFu : 0u) & vd_);
                    int rowoff = vm ? ((d2 * 8 + h2) * 8) : 0;
                    uint4 rw = *(const uint4*)(Vsh + c * 520 + rowoff);
                    unsigned r0 = rw.x, r1 = rw.y, r2 = rw.z, r3 = rw.w;
                    unsigned ms0 = r0 << 16;
                    unsigned ms1 = (r1 << 16) | (r0 >> 16);
                    unsigned ms2 = (r2 << 16) | (r1 >> 16);
                    unsigned ms3 = (r3 << 16) | (r2 >> 16);
                    unsigned ms4 = r3 >> 16;
                    int t0 = kd * 9 + kh * 3;
                    f16x2 w0 = uAsH(wdp[c * 27 + t0]     & vm);
                    f16x2 w1 = uAsH(wdp[c * 27 + t0 + 1] & vm);
                    f16x2 w2 = uAsH(wdp[c * 27 + t0 + 2] & vm);
                    f16x2* acc2 = (kd == 0) ? A0 : ((kd == 1) ? A1 : A2);
                    acc2[0] = uAsH(ms0) * w0 + acc2[0];
                    acc2[1] = uAsH(ms1) * w0 + acc2[1];
                    acc2[2] = uAsH(ms2) * w0 + acc2[2];
                    acc2[3] = uAsH(ms3) * w0 + acc2[3];
                    acc2[0] = uAsH(r0) * w1 + acc2[0];
                    acc2[1] = uAsH(r1) * w1 + acc2[1];
                    acc2[2] = uAsH(r2) * w1 + acc2[2];
                    acc2[3] = uAsH(r3) * w1 + acc2[3];
                    acc2[0] = uAsH(ms1) * w2 + acc2[0];
                    acc2[1] = uAsH(ms2) * w2 + acc2[1];
                    acc2[2] = uAsH(ms3) * w2 + acc2[2];
                    acc2[3] = uAsH(ms4) * w2 + acc2[3];
                }
            }
            float bv = bld[c];
            unsigned ow[4];
            #pragma unroll
            for (int p = 0; p < 4; ++p) {
                float lo = (float)A0[p].x + (float)A1[p].x + (float)A2[p].x + bv;
                float hi = (float)A0[p].y + (float)A1[p].y + (float)A2[p].y + bv;
                f16x2 hp = { (f16)lo, (f16)hi };
                ow[p] = hAsU(hp);
            }
            *(uint4*)(outb + (size_t)(ch0 + c) * 512 + dh * 8) = make_uint4(ow[0], ow[1], ow[2], ow[3]);
        }
    }
}

// ---------------------------------------------------------------------------
// K3 v7 (record config): single-pass softmax, kf + vb hoisted per tile,
// qf streamed per q-group, 512 threads (8 waves x 64 q-rows). grid 512.
// ---------------------------------------------------------------------------
__global__ __launch_bounds__(512) void k3_attn(
    const f16* __restrict__ qF, const f16* __restrict__ kF, const f16* __restrict__ vF,
    float* __restrict__ outp)
{
    __shared__ __align__(16) f16 Ksh[512 * 104];   // 106496 B
    __shared__ __align__(16) f16 Psh[8 * 1152];    // 8 waves x [16 q][72 k]

    const int tid = threadIdx.x;
    const int b = blockIdx.x;
    const int wv_ = tid >> 6, lane = tid & 63, lr = lane & 15, lk = lane >> 4;

    const f16* qg = qF + ((size_t)b * 512 + wv_ * 64) * 96;
    const f16* kg = kF + (size_t)b * 512 * 96;
    const f16* vg = vF + (size_t)b * 96 * 512;

    const float scl = 0.14724447f;   // log2(e)/sqrt(96), applied post-MFMA

    #pragma unroll
    for (int it = 0; it < 12; ++it) {
        int i = tid * 8 + it * 4096;
        int r = i / 96, c = i % 96;
        *(uint4*)(Ksh + r * 104 + c) = *(const uint4*)(kg + i);
    }
    __syncthreads();

    float sum_p[4] = {0.f, 0.f, 0.f, 0.f};
    f32x4 accO[4][6];
    #pragma unroll
    for (int qg2 = 0; qg2 < 4; ++qg2)
        #pragma unroll
        for (int cg = 0; cg < 6; ++cg) accO[qg2][cg] = f32x4{0.f, 0.f, 0.f, 0.f};

    f16* psw = Psh + wv_ * 1152;
    uint2* psw2 = (uint2*)psw;

    for (int t = 0; t < 8; ++t) {
        f16x8 kf[3][4];
        #pragma unroll
        for (int ks3 = 0; ks3 < 3; ++ks3)
            #pragma unroll
            for (int f = 0; f < 4; ++f)
                kf[ks3][f] = *(const f16x8*)(Ksh + (t * 64 + f * 16 + lr) * 104 + ks3 * 32 + lk * 8);
        f16x8 vb[2][6];
        #pragma unroll
        for (int ks2 = 0; ks2 < 2; ++ks2)
            #pragma unroll
            for (int cg = 0; cg < 6; ++cg)
                vb[ks2][cg] = *(const f16x8*)(vg + (size_t)(cg * 16 + lr) * 512
                                                 + t * 64 + ks2 * 32 + lk * 8);
        #pragma unroll
        for (int qg2 = 0; qg2 < 4; ++qg2) {
            f16x8 qf3[3];
            #pragma unroll
            for (int ks3 = 0; ks3 < 3; ++ks3)
                qf3[ks3] = *(const f16x8*)(qg + (qg2 * 16 + lr) * 96 + ks3 * 32 + lk * 8);
            f32x4 sa[4];
            #pragma unroll
            for (int f = 0; f < 4; ++f) sa[f] = f32x4{0.f, 0.f, 0.f, 0.f};
            #pragma unroll
            for (int ks3 = 0; ks3 < 3; ++ks3)
                #pragma unroll
                for (int f = 0; f < 4; ++f)
                    sa[f] = __builtin_amdgcn_mfma_f32_16x16x32_f16(kf[ks3][f], qf3[ks3], sa[f], 0, 0, 0);
            #pragma unroll
            for (int f = 0; f < 4; ++f) {
                float e0 = __builtin_amdgcn_exp2f(sa[f][0] * scl);
                float e1 = __builtin_amdgcn_exp2f(sa[f][1] * scl);
                float e2 = __builtin_amdgcn_exp2f(sa[f][2] * scl);
                float e3 = __builtin_amdgcn_exp2f(sa[f][3] * scl);
                sum_p[qg2] += (e0 + e1) + (e2 + e3);
                uint2 pk;
                pk.x = pAsU(__builtin_amdgcn_cvt_pkrtz(e0, e1));
                pk.y = pAsU(__builtin_amdgcn_cvt_pkrtz(e2, e3));
                psw2[lr * 18 + f * 4 + lk] = pk;
            }
            #pragma unroll
            for (int ks2 = 0; ks2 < 2; ++ks2) {
                f16x8 pb = *(const f16x8*)(psw + lr * 72 + ks2 * 32 + lk * 8);
                #pragma unroll
                for (int cg = 0; cg < 6; ++cg)
                    accO[qg2][cg] = __builtin_amdgcn_mfma_f32_16x16x32_f16(
                        vb[ks2][cg], pb, accO[qg2][cg], 0, 0, 0);
            }
        }
    }
    #pragma unroll
    for (int qg2 = 0; qg2 < 4; ++qg2) {
        sum_p[qg2] += __shfl_xor(sum_p[qg2], 16);
        sum_p[qg2] += __shfl_xor(sum_p[qg2], 32);
    }

    #pragma unroll
    for (int qg2 = 0; qg2 < 4; ++qg2) {
        const float inv = 1.0f / sum_p[qg2];
        float* og = outp + ((size_t)b * 512 + wv_ * 64 + qg2 * 16 + lr) * 96;
        #pragma unroll
        for (int cg = 0; cg < 6; ++cg) {
            float4 o4 = make_float4(accO[qg2][cg][0] * inv, accO[qg2][cg][1] * inv,
                                    accO[qg2][cg][2] * inv, accO[qg2][cg][3] * inv);
            *(float4*)(og + cg * 16 + lk * 4) = o4;
        }
    }
}

extern "C" void kernel_launch(void* const* d_in, const int* in_sizes, int n_in,
                              void* d_out, int out_size, void* d_ws, size_t ws_size,
                              hipStream_t stream) {
    const float* x   = (const float*)d_in[0];
    const float* wq1 = (const float*)d_in[1];
    const float* bq1 = (const float*)d_in[2];
    const float* wk1 = (const float*)d_in[3];
    const float* bk1 = (const float*)d_in[4];
    const float* wv1 = (const float*)d_in[5];
    const float* bv1 = (const float*)d_in[6];
    const float* wqd = (const float*)d_in[7];
    const float* bqd = (const float*)d_in[8];
    const float* wkd = (const float*)d_in[9];
    const float* bkd = (const float*)d_in[10];
    const float* wvd = (const float*)d_in[11];
    const float* bvd = (const float*)d_in[12];

    f16* ws = (f16*)d_ws;
    f16* q  = ws;
    f16* k  = ws + PL;
    f16* v  = ws + 2 * PL;
    f16* xh = ws + 3 * PL;

    kcvt<<<3072, 256, 0, stream>>>(x, xh);
    k12_fused<<<3072, 512, 0, stream>>>(xh, wq1, bq1, wk1, bk1, wv1, bv1,
                                        wqd, bqd, wkd, bkd, wvd, bvd, q, k, v);
    k3_attn<<<512, 512, 0, stream>>>(q, k, v, (float*)d_out);
}